// Round 3
// baseline (1526.248 us; speedup 1.0000x reference)
//
#include <hip/hip_runtime.h>
#include <hip/hip_bf16.h>

// Problem constants
#define N_ROWS 65536   // 16*4096
#define EDIM   512
#define NCODES 1024

// ws layout (floats): [0]=loss, [1..1025)=counts, [1025..2049)=enorm, [2049..)=znorm
#define WS_LOSS   0
#define WS_COUNTS 1
#define WS_ENORM  1025
#define WS_ZNORM  2049
#define WS_AMBCNT (2049 + 65536)          // int, 67585
#define WS_WINNER (WS_AMBCNT + 1)         // 65536 ints
#define WS_AMBLST (WS_WINNER + 65536)     // CAP ints
#define AMB_CAP   16384
#define WS_E2_OFF (1u << 20)              // e2 (bf16 hi/lo) at ws + 1 MiB, 2 MiB
#define WS_FAST_BYTES (3u * 1024u * 1024u + 4096u)

#define AMB_EPS 2.5e-4f

typedef short short8 __attribute__((ext_vector_type(8)));
typedef float f32x4  __attribute__((ext_vector_type(4)));

static __device__ __forceinline__ unsigned short f2bf(float f) {
    unsigned u = __float_as_uint(f);
    u += 0x7FFFu + ((u >> 16) & 1u);   // RNE (finite inputs only)
    return (unsigned short)(u >> 16);
}
static __device__ __forceinline__ float bf2f(unsigned short h) {
    return __uint_as_float(((unsigned)h) << 16);
}

// ---------------- kernel: codebook norms + zero accumulators ----------------
__global__ __launch_bounds__(256) void vq_prep(const float* __restrict__ cb,
                                               float* __restrict__ ws) {
    int j = blockIdx.x;
    int tid = threadIdx.x;
    float2 v = *(const float2*)&cb[(size_t)j * EDIM + tid * 2];
    float s = v.x * v.x + v.y * v.y;
    #pragma unroll
    for (int off = 32; off > 0; off >>= 1) s += __shfl_down(s, off);
    __shared__ float ls[4];
    int wave = tid >> 6, lane = tid & 63;
    if (lane == 0) ls[wave] = s;
    __syncthreads();
    if (tid == 0) {
        ws[WS_ENORM + j] = ls[0] + ls[1] + ls[2] + ls[3];
        ws[WS_COUNTS + j] = 0.0f;
        if (j == 0) {
            ws[WS_LOSS] = 0.0f;
            ((int*)ws)[WS_AMBCNT] = 0;
        }
    }
}

// ---------------- kernel: per-row ||z||^2, numpy-pairwise bit-exact ----------------
__global__ __launch_bounds__(256) void vq_znorm(const float* __restrict__ z,
                                                float* __restrict__ ws) {
    int tid  = threadIdx.x;
    int lrow = tid >> 5;
    int c    = tid & 31;
    long row = (long)blockIdx.x * 8 + lrow;
    const float* p = z + row * EDIM + (c >> 3) * 128 + (c & 7);
    float r = p[0] * p[0];
    #pragma unroll
    for (int i = 1; i < 16; ++i) {
        float v = p[i * 8];
        r += v * v;
    }
    r += __shfl_xor(r, 1);
    r += __shfl_xor(r, 2);
    r += __shfl_xor(r, 4);
    r += __shfl_xor(r, 8);
    r += __shfl_xor(r, 16);
    if (c == 0) ws[WS_ZNORM + row] = r;
}

// ---------------- kernel: z -> bf16 hi/lo panels ----------------
// layout: [panel p][kc 0..15][plane hi/lo][row 0..127][k 0..31] ushort
__global__ __launch_bounds__(256) void vq_convz(const float* __restrict__ z,
                                                unsigned short* __restrict__ z2) {
    const int tid = threadIdx.x;
    const int p = blockIdx.x;
    const long row0 = (long)p * 128;
    const int row = tid >> 1, half = tid & 1;
    for (int kc = 0; kc < 16; ++kc) {
        const float* src = z + (row0 + row) * EDIM + kc * 32 + half * 16;
        float f[16];
        #pragma unroll
        for (int q = 0; q < 4; ++q) {
            float4 v = ((const float4*)src)[q];
            f[q*4+0] = v.x; f[q*4+1] = v.y; f[q*4+2] = v.z; f[q*4+3] = v.w;
        }
        unsigned hi[8], lo[8];
        #pragma unroll
        for (int q = 0; q < 8; ++q) {
            unsigned short h0 = f2bf(f[2*q]);
            unsigned short h1 = f2bf(f[2*q+1]);
            unsigned short l0 = f2bf(f[2*q]   - bf2f(h0));
            unsigned short l1 = f2bf(f[2*q+1] - bf2f(h1));
            hi[q] = (unsigned)h0 | ((unsigned)h1 << 16);
            lo[q] = (unsigned)l0 | ((unsigned)l1 << 16);
        }
        size_t base = ((size_t)(p * 16 + kc) * 2) * 4096;
        unsigned* dhi = (unsigned*)(z2 + base        + row * 32 + half * 16);
        unsigned* dlo = (unsigned*)(z2 + base + 4096 + row * 32 + half * 16);
        ((uint4*)dhi)[0] = make_uint4(hi[0], hi[1], hi[2], hi[3]);
        ((uint4*)dhi)[1] = make_uint4(hi[4], hi[5], hi[6], hi[7]);
        ((uint4*)dlo)[0] = make_uint4(lo[0], lo[1], lo[2], lo[3]);
        ((uint4*)dlo)[1] = make_uint4(lo[4], lo[5], lo[6], lo[7]);
    }
}

// ---------------- kernel: cb -> bf16 hi/lo panels ----------------
// layout: [cc 0..7][kc 0..15][plane][code 0..127][k 0..31]
__global__ __launch_bounds__(256) void vq_convcb(const float* __restrict__ cb,
                                                 unsigned short* __restrict__ e2) {
    const int tid = threadIdx.x;
    const int cc = blockIdx.x;
    const int row = tid >> 1, half = tid & 1;
    for (int kc = 0; kc < 16; ++kc) {
        const float* src = cb + (size_t)(cc * 128 + row) * EDIM + kc * 32 + half * 16;
        float f[16];
        #pragma unroll
        for (int q = 0; q < 4; ++q) {
            float4 v = ((const float4*)src)[q];
            f[q*4+0] = v.x; f[q*4+1] = v.y; f[q*4+2] = v.z; f[q*4+3] = v.w;
        }
        unsigned hi[8], lo[8];
        #pragma unroll
        for (int q = 0; q < 8; ++q) {
            unsigned short h0 = f2bf(f[2*q]);
            unsigned short h1 = f2bf(f[2*q+1]);
            unsigned short l0 = f2bf(f[2*q]   - bf2f(h0));
            unsigned short l1 = f2bf(f[2*q+1] - bf2f(h1));
            hi[q] = (unsigned)h0 | ((unsigned)h1 << 16);
            lo[q] = (unsigned)l0 | ((unsigned)l1 << 16);
        }
        size_t base = ((size_t)(cc * 16 + kc) * 2) * 4096;
        unsigned* dhi = (unsigned*)(e2 + base        + row * 32 + half * 16);
        unsigned* dlo = (unsigned*)(e2 + base + 4096 + row * 32 + half * 16);
        ((uint4*)dhi)[0] = make_uint4(hi[0], hi[1], hi[2], hi[3]);
        ((uint4*)dhi)[1] = make_uint4(hi[4], hi[5], hi[6], hi[7]);
        ((uint4*)dlo)[0] = make_uint4(lo[0], lo[1], lo[2], lo[3]);
        ((uint4*)dlo)[1] = make_uint4(lo[4], lo[5], lo[6], lo[7]);
    }
}

// ---------------- main MFMA kernel: d-hat + per-row top2 + ambiguity ----------------
// block tile 128 rows x 128 codes (per cc), wave tile 64x64, mfma 16x16x32 bf16
__global__ __launch_bounds__(256, 2) void vq_mfma(const unsigned short* __restrict__ z2,
                                                  const unsigned short* __restrict__ e2,
                                                  const float* __restrict__ ws,
                                                  int* __restrict__ winner,
                                                  int* __restrict__ amb_count,
                                                  int* __restrict__ amb_list) {
    __shared__ unsigned short stage[16384];   // 32 KB: z chunk (16KB) + e chunk (16KB)
    __shared__ float fv1[2][128];
    __shared__ float fv2[2][128];
    __shared__ int   fc1[2][128];

    const int tid = threadIdx.x;
    const int lane = tid & 63, w = tid >> 6;
    const int rw = (w & 1) * 64, cw = (w >> 1) * 64;
    const int ml = lane & 15, kg = lane >> 4;
    const long row0 = (long)blockIdx.x * 128;
    const float* __restrict__ enorm = ws + WS_ENORM;

    float v1[16], v2[16];
    int   c1[16];
    #pragma unroll
    for (int i = 0; i < 16; ++i) { v1[i] = INFINITY; v2[i] = INFINITY; c1[i] = 0; }

    const unsigned short* zt = stage;
    const unsigned short* et = stage + 8192;

    for (int cc = 0; cc < 8; ++cc) {
        f32x4 acc[4][4];
        #pragma unroll
        for (int rt = 0; rt < 4; ++rt)
            #pragma unroll
            for (int ct = 0; ct < 4; ++ct)
                acc[rt][ct] = (f32x4){0.f, 0.f, 0.f, 0.f};

        for (int kc = 0; kc < 16; ++kc) {
            __syncthreads();
            const uint4* zsrc = (const uint4*)(z2 + (size_t)(blockIdx.x * 16 + kc) * 8192);
            const uint4* esrc = (const uint4*)(e2 + (size_t)(cc * 16 + kc) * 8192);
            uint4* st = (uint4*)stage;
            #pragma unroll
            for (int it = 0; it < 4; ++it) {
                int i = it * 256 + tid;
                st[i] = zsrc[i];
            }
            #pragma unroll
            for (int it = 0; it < 4; ++it) {
                int i = it * 256 + tid;
                st[1024 + i] = esrc[i];
            }
            __syncthreads();

            short8 a[4][2], b[4][2];
            #pragma unroll
            for (int rt = 0; rt < 4; ++rt) {
                a[rt][0] = *(const short8*)&zt[        (rw + rt * 16 + ml) * 32 + kg * 8];
                a[rt][1] = *(const short8*)&zt[4096 + (rw + rt * 16 + ml) * 32 + kg * 8];
            }
            #pragma unroll
            for (int ct = 0; ct < 4; ++ct) {
                b[ct][0] = *(const short8*)&et[        (cw + ct * 16 + ml) * 32 + kg * 8];
                b[ct][1] = *(const short8*)&et[4096 + (cw + ct * 16 + ml) * 32 + kg * 8];
            }
            #pragma unroll
            for (int rt = 0; rt < 4; ++rt)
                #pragma unroll
                for (int ct = 0; ct < 4; ++ct) {
                    acc[rt][ct] = __builtin_amdgcn_mfma_f32_16x16x32_bf16(a[rt][0], b[ct][0], acc[rt][ct], 0, 0, 0);
                    acc[rt][ct] = __builtin_amdgcn_mfma_f32_16x16x32_bf16(a[rt][0], b[ct][1], acc[rt][ct], 0, 0, 0);
                    acc[rt][ct] = __builtin_amdgcn_mfma_f32_16x16x32_bf16(a[rt][1], b[ct][0], acc[rt][ct], 0, 0, 0);
                }
        }

        // epilogue: d-hat = enorm - 2*dot, per-lane top2 per row
        float en[4];
        #pragma unroll
        for (int ct = 0; ct < 4; ++ct) en[ct] = enorm[cc * 128 + cw + ct * 16 + ml];
        #pragma unroll
        for (int rt = 0; rt < 4; ++rt)
            #pragma unroll
            for (int ct = 0; ct < 4; ++ct) {
                int code = cc * 128 + cw + ct * 16 + ml;
                #pragma unroll
                for (int reg = 0; reg < 4; ++reg) {
                    float d = fmaf(-2.0f, acc[rt][ct][reg], en[ct]);
                    int i = rt * 4 + reg;
                    bool lt1 = d < v1[i];
                    bool lt2 = d < v2[i];
                    v2[i] = lt1 ? v1[i] : (lt2 ? d : v2[i]);
                    v1[i] = lt1 ? d : v1[i];
                    c1[i] = lt1 ? code : c1[i];
                }
            }
    }

    // cross-lane merge among the 16 lanes (same kg) sharing each row
    #pragma unroll
    for (int i = 0; i < 16; ++i) {
        #pragma unroll
        for (int off = 1; off < 16; off <<= 1) {
            float ov1 = __shfl_xor(v1[i], off);
            int   oc1 = __shfl_xor(c1[i], off);
            float ov2 = __shfl_xor(v2[i], off);
            bool take = (ov1 < v1[i]) || (ov1 == v1[i] && oc1 < c1[i]);
            float nv2 = take ? fminf(v1[i], ov2) : fminf(v2[i], ov1);
            v1[i] = take ? ov1 : v1[i];
            c1[i] = take ? oc1 : c1[i];
            v2[i] = nv2;
        }
    }
    __syncthreads();
    if (ml == 0) {
        #pragma unroll
        for (int i = 0; i < 16; ++i) {
            int row = rw + (i >> 2) * 16 + kg * 4 + (i & 3);
            fv1[w >> 1][row] = v1[i];
            fv2[w >> 1][row] = v2[i];
            fc1[w >> 1][row] = c1[i];
        }
    }
    __syncthreads();
    if (tid < 128) {
        float a1 = fv1[0][tid], a2 = fv2[0][tid];
        int   ac = fc1[0][tid];
        float b1 = fv1[1][tid], b2 = fv2[1][tid];
        int   bc = fc1[1][tid];
        bool take = (b1 < a1) || (b1 == a1 && bc < ac);
        float V1 = take ? b1 : a1;
        int   C1 = take ? bc : ac;
        float V2 = take ? fminf(a1, b2) : fminf(a2, b1);
        winner[row0 + tid] = C1;
        if (V2 - V1 < AMB_EPS) {
            int p = atomicAdd(amb_count, 1);
            if (p < AMB_CAP) amb_list[p] = (int)(row0 + tid);
        }
    }
}

// ---------------- recheck: exact R2-chain argmin for ambiguous rows ----------------
__global__ __launch_bounds__(256) void vq_recheck(const float* __restrict__ z,
                                                  const float* __restrict__ cb,
                                                  const float* __restrict__ ws,
                                                  int* __restrict__ winner,
                                                  const int* __restrict__ amb_count,
                                                  const int* __restrict__ amb_list) {
    __shared__ float zrow[EDIM];
    __shared__ float rd[256];
    __shared__ int   ri[256];
    const int tid = threadIdx.x;
    const float* __restrict__ enorm = ws + WS_ENORM;
    int n = *amb_count;
    if (n > AMB_CAP) n = AMB_CAP;
    for (int ii = blockIdx.x; ii < n; ii += gridDim.x) {
        int row = amb_list[ii];
        __syncthreads();
        zrow[tid] = z[(long)row * EDIM + tid];
        zrow[tid + 256] = z[(long)row * EDIM + tid + 256];
        __syncthreads();
        float zn = ws[WS_ZNORM + row];
        float bd = INFINITY;
        int   bc = 0;
        for (int cc = 0; cc < 4; ++cc) {
            int code = cc * 256 + tid;
            const float* e = cb + (size_t)code * EDIM;
            float acc = 0.0f;
            for (int k0 = 0; k0 < EDIM; k0 += 32) {
                float ain = 0.0f;
                #pragma unroll
                for (int kk = 0; kk < 32; ++kk)
                    ain = fmaf(zrow[k0 + kk], e[k0 + kk], ain);
                acc += ain;
            }
            float t = zn + enorm[code];
            float d = t - 2.0f * acc;
            if (d < bd) { bd = d; bc = code; }   // codes ascending per thread
        }
        rd[tid] = bd; ri[tid] = bc;
        __syncthreads();
        for (int s = 128; s > 0; s >>= 1) {
            if (tid < s) {
                if (rd[tid + s] < rd[tid] ||
                    (rd[tid + s] == rd[tid] && ri[tid + s] < ri[tid])) {
                    rd[tid] = rd[tid + s]; ri[tid] = ri[tid + s];
                }
            }
            __syncthreads();
        }
        if (tid == 0) winner[row] = ri[0];
    }
}

// ---------------- emit: idx, counts, z_q_st, loss ----------------
__global__ __launch_bounds__(256) void vq_emit(const float* __restrict__ z,
                                               const float* __restrict__ cb,
                                               const int* __restrict__ winner,
                                               float* __restrict__ ws,
                                               float* __restrict__ out_zq,
                                               float* __restrict__ out_idx) {
    __shared__ float lred[4];
    const int tid = threadIdx.x;
    const long row0 = (long)blockIdx.x * 128;
    if (tid < 128) {
        int wi = winner[row0 + tid];
        out_idx[row0 + tid] = (float)wi;
        atomicAdd(&ws[WS_COUNTS + wi], 1.0f);
    }
    float lsum = 0.0f;
    for (int r = 0; r < 128; ++r) {
        int wv = winner[row0 + r];
        float2 e  = *(const float2*)&cb[(size_t)wv * EDIM + tid * 2];
        float2 zz = *(const float2*)&z[(row0 + r) * EDIM + tid * 2];
        float d0 = e.x - zz.x, d1 = e.y - zz.y;
        float2 o; o.x = zz.x + d0; o.y = zz.y + d1;
        *(float2*)&out_zq[(row0 + r) * EDIM + tid * 2] = o;
        lsum = fmaf(d0, d0, fmaf(d1, d1, lsum));
    }
    #pragma unroll
    for (int off = 32; off > 0; off >>= 1) lsum += __shfl_down(lsum, off);
    int wave = tid >> 6, lane = tid & 63;
    if (lane == 0) lred[wave] = lsum;
    __syncthreads();
    if (tid == 0) atomicAdd(&ws[WS_LOSS], lred[0] + lred[1] + lred[2] + lred[3]);
}

// ---------------- finalize loss + perplexity ----------------
__global__ __launch_bounds__(1024) void vq_final(const float* __restrict__ ws,
                                                 float* __restrict__ out,
                                                 long off_perp) {
    int tid = threadIdx.x;
    float c = ws[WS_COUNTS + tid] * (1.0f / (float)N_ROWS);
    float t = c * logf(c + 1e-10f);
    #pragma unroll
    for (int off = 32; off > 0; off >>= 1) t += __shfl_down(t, off);
    __shared__ float ls[16];
    int wave = tid >> 6, lane = tid & 63;
    if (lane == 0) ls[wave] = t;
    __syncthreads();
    if (tid == 0) {
        float h = 0.0f;
        #pragma unroll
        for (int i = 0; i < 16; ++i) h += ls[i];
        out[off_perp] = expf(-h);
        out[0] = ws[WS_LOSS] * 1.25f / (float)((long)N_ROWS * EDIM);
    }
}

// ================= fallback: round-2 verified fp32 main kernel =================
#define ROWS_PER_BLOCK 128
#define CODE_CHUNK     64
#define KCHUNK         32
#define ZSTRIDE        132
#define ESTRIDE        68

__global__ __launch_bounds__(256) void vq_main_fb(const float* __restrict__ z,
                                                  const float* __restrict__ cb,
                                                  float* __restrict__ ws,
                                                  float* __restrict__ out_zq,
                                                  float* __restrict__ out_idx) {
    __shared__ float zt[KCHUNK * ZSTRIDE];
    __shared__ float et[KCHUNK * ESTRIDE];
    __shared__ float red_d[ROWS_PER_BLOCK * 8];
    __shared__ int   red_i[ROWS_PER_BLOCK * 8];
    __shared__ int   winner[ROWS_PER_BLOCK];
    __shared__ float lred[4];

    const int tid = threadIdx.x;
    const int tx = tid & 7;
    const int ty = tid >> 3;
    const long row0 = (long)blockIdx.x * ROWS_PER_BLOCK;
    const float* __restrict__ enorm = ws + WS_ENORM;
    const float* __restrict__ znorm = ws + WS_ZNORM;

    float zn[4];
    #pragma unroll
    for (int i = 0; i < 4; ++i) zn[i] = znorm[row0 + ty * 4 + i];

    float best[4];
    int   bidx[4];
    #pragma unroll
    for (int i = 0; i < 4; ++i) { best[i] = INFINITY; bidx[i] = 0; }

    const int kq    = (tid & 7) * 4;
    const int rbase = tid >> 3;

    for (int c = 0; c < NCODES; c += CODE_CHUNK) {
        float acc[4][8];
        #pragma unroll
        for (int i = 0; i < 4; ++i)
            #pragma unroll
            for (int j = 0; j < 8; ++j) acc[i][j] = 0.0f;

        for (int k0 = 0; k0 < EDIM; k0 += KCHUNK) {
            __syncthreads();
            #pragma unroll
            for (int it = 0; it < 4; ++it) {
                int r = rbase + it * 32;
                float4 v = *(const float4*)&z[(row0 + r) * EDIM + k0 + kq];
                zt[(kq + 0) * ZSTRIDE + r] = v.x;
                zt[(kq + 1) * ZSTRIDE + r] = v.y;
                zt[(kq + 2) * ZSTRIDE + r] = v.z;
                zt[(kq + 3) * ZSTRIDE + r] = v.w;
            }
            #pragma unroll
            for (int it = 0; it < 2; ++it) {
                int e = rbase + it * 32;
                float4 v = *(const float4*)&cb[(size_t)(c + e) * EDIM + k0 + kq];
                et[(kq + 0) * ESTRIDE + e] = v.x;
                et[(kq + 1) * ESTRIDE + e] = v.y;
                et[(kq + 2) * ESTRIDE + e] = v.z;
                et[(kq + 3) * ESTRIDE + e] = v.w;
            }
            __syncthreads();
            float ain[4][8];
            #pragma unroll
            for (int i = 0; i < 4; ++i)
                #pragma unroll
                for (int j = 0; j < 8; ++j) ain[i][j] = 0.0f;
            #pragma unroll
            for (int kk = 0; kk < KCHUNK; ++kk) {
                float4 zv = *(const float4*)&zt[kk * ZSTRIDE + ty * 4];
                float4 e0 = *(const float4*)&et[kk * ESTRIDE + tx * 8];
                float4 e1 = *(const float4*)&et[kk * ESTRIDE + tx * 8 + 4];
                float za[4] = {zv.x, zv.y, zv.z, zv.w};
                float ea[8] = {e0.x, e0.y, e0.z, e0.w, e1.x, e1.y, e1.z, e1.w};
                #pragma unroll
                for (int i = 0; i < 4; ++i)
                    #pragma unroll
                    for (int j = 0; j < 8; ++j)
                        ain[i][j] = fmaf(za[i], ea[j], ain[i][j]);
            }
            #pragma unroll
            for (int i = 0; i < 4; ++i)
                #pragma unroll
                for (int j = 0; j < 8; ++j) acc[i][j] += ain[i][j];
        }
        #pragma unroll
        for (int j = 0; j < 8; ++j) {
            int code = c + tx * 8 + j;
            float en = enorm[code];
            #pragma unroll
            for (int i = 0; i < 4; ++i) {
                float t = zn[i] + en;
                float d = t - 2.0f * acc[i][j];
                if (d < best[i]) { best[i] = d; bidx[i] = code; }
            }
        }
    }

    __syncthreads();
    #pragma unroll
    for (int i = 0; i < 4; ++i) {
        red_d[(ty * 4 + i) * 8 + tx] = best[i];
        red_i[(ty * 4 + i) * 8 + tx] = bidx[i];
    }
    __syncthreads();
    if (tid < ROWS_PER_BLOCK) {
        float bd = red_d[tid * 8];
        int   bi = red_i[tid * 8];
        #pragma unroll
        for (int t = 1; t < 8; ++t) {
            float dv = red_d[tid * 8 + t];
            int   iv = red_i[tid * 8 + t];
            if (dv < bd || (dv == bd && iv < bi)) { bd = dv; bi = iv; }
        }
        winner[tid] = bi;
        out_idx[row0 + tid] = (float)bi;
        atomicAdd(&ws[WS_COUNTS + bi], 1.0f);
    }
    __syncthreads();

    float lsum = 0.0f;
    for (int r = 0; r < ROWS_PER_BLOCK; ++r) {
        int w = winner[r];
        float2 e  = *(const float2*)&cb[(size_t)w * EDIM + tid * 2];
        float2 zz = *(const float2*)&z[(row0 + r) * EDIM + tid * 2];
        float d0 = e.x - zz.x, d1 = e.y - zz.y;
        float2 o; o.x = zz.x + d0; o.y = zz.y + d1;
        *(float2*)&out_zq[(row0 + r) * EDIM + tid * 2] = o;
        lsum = fmaf(d0, d0, fmaf(d1, d1, lsum));
    }
    #pragma unroll
    for (int off = 32; off > 0; off >>= 1) lsum += __shfl_down(lsum, off);
    int wave = tid >> 6, lane = tid & 63;
    if (lane == 0) lred[wave] = lsum;
    __syncthreads();
    if (tid == 0) atomicAdd(&ws[WS_LOSS], lred[0] + lred[1] + lred[2] + lred[3]);
}

extern "C" void kernel_launch(void* const* d_in, const int* in_sizes, int n_in,
                              void* d_out, int out_size, void* d_ws, size_t ws_size,
                              hipStream_t stream) {
    const float* z  = (const float*)d_in[0];
    const float* cb = (const float*)d_in[1];
    float* out = (float*)d_out;
    float* ws  = (float*)d_ws;

    float* out_zq  = out + 1;
    float* out_idx = out + 1 + (long)N_ROWS * EDIM;
    long   off_perp = 1 + (long)N_ROWS * EDIM + N_ROWS;

    hipLaunchKernelGGL(vq_prep, dim3(NCODES), dim3(256), 0, stream, cb, ws);
    hipLaunchKernelGGL(vq_znorm, dim3(N_ROWS / 8), dim3(256), 0, stream, z, ws);

    if (ws_size >= (size_t)WS_FAST_BYTES) {
        // z2 scratch lives in the z_q output region (16B-aligned at out+4;
        // spills 12 B into the idx region, which emit rewrites afterwards)
        unsigned short* z2 = (unsigned short*)(out + 4);
        unsigned short* e2 = (unsigned short*)((char*)d_ws + WS_E2_OFF);
        int* winner    = ((int*)ws) + WS_WINNER;
        int* amb_count = ((int*)ws) + WS_AMBCNT;
        int* amb_list  = ((int*)ws) + WS_AMBLST;

        hipLaunchKernelGGL(vq_convz, dim3(N_ROWS / 128), dim3(256), 0, stream, z, z2);
        hipLaunchKernelGGL(vq_convcb, dim3(8), dim3(256), 0, stream, cb, e2);
        hipLaunchKernelGGL(vq_mfma, dim3(N_ROWS / 128), dim3(256), 0, stream,
                           z2, e2, ws, winner, amb_count, amb_list);
        hipLaunchKernelGGL(vq_recheck, dim3(128), dim3(256), 0, stream,
                           z, cb, ws, winner, amb_count, amb_list);
        hipLaunchKernelGGL(vq_emit, dim3(N_ROWS / 128), dim3(256), 0, stream,
                           z, cb, winner, ws, out_zq, out_idx);
    } else {
        hipLaunchKernelGGL(vq_main_fb, dim3(N_ROWS / 128), dim3(256), 0, stream,
                           z, cb, ws, out_zq, out_idx);
    }
    hipLaunchKernelGGL(vq_final, dim3(1), dim3(1024), 0, stream, ws, out, off_perp);
}

// Round 4
// 698.909 us; speedup vs baseline: 2.1838x; 2.1838x over previous
//
#include <hip/hip_runtime.h>
#include <hip/hip_bf16.h>

// Problem constants
#define N_ROWS 65536   // 16*4096
#define EDIM   512
#define NCODES 1024

// ws layout (floats): [0]=loss, [1..1025)=counts, [1025..2049)=enorm, [2049..)=znorm
#define WS_LOSS   0
#define WS_COUNTS 1
#define WS_ENORM  1025
#define WS_ZNORM  2049
#define WS_AMBCNT (2049 + 65536)          // int, 67585
#define WS_WINNER (WS_AMBCNT + 1)         // 65536 ints
#define WS_AMBLST (WS_WINNER + 65536)     // CAP ints
#define AMB_CAP   32768
#define WS_E2_OFF (1u << 20)              // e2 (bf16 hi/lo) at ws + 1 MiB, 2 MiB
#define WS_FAST_BYTES (3u * 1024u * 1024u + 4096u)

// δ bound: ref quantization 2×ULP(512)/2 = 6.1e-5, ref-vs-my dot ≈ 6.3e-6 → pair 1.35e-4
#define AMB_EPS 1.6e-4f

typedef short short8 __attribute__((ext_vector_type(8)));
typedef float f32x4  __attribute__((ext_vector_type(4)));

#define AS1C(p) ((const __attribute__((address_space(1))) void*)(p))
#define AS3(p)  ((__attribute__((address_space(3))) void*)(p))

static __device__ __forceinline__ unsigned short f2bf(float f) {
    unsigned u = __float_as_uint(f);
    u += 0x7FFFu + ((u >> 16) & 1u);   // RNE (finite inputs only)
    return (unsigned short)(u >> 16);
}
static __device__ __forceinline__ float bf2f(unsigned short h) {
    return __uint_as_float(((unsigned)h) << 16);
}

// ---------------- kernel: codebook norms + zero accumulators ----------------
__global__ __launch_bounds__(256) void vq_prep(const float* __restrict__ cb,
                                               float* __restrict__ ws) {
    int j = blockIdx.x;
    int tid = threadIdx.x;
    float2 v = *(const float2*)&cb[(size_t)j * EDIM + tid * 2];
    float s = v.x * v.x + v.y * v.y;
    #pragma unroll
    for (int off = 32; off > 0; off >>= 1) s += __shfl_down(s, off);
    __shared__ float ls[4];
    int wave = tid >> 6, lane = tid & 63;
    if (lane == 0) ls[wave] = s;
    __syncthreads();
    if (tid == 0) {
        ws[WS_ENORM + j] = ls[0] + ls[1] + ls[2] + ls[3];
        ws[WS_COUNTS + j] = 0.0f;
        if (j == 0) {
            ws[WS_LOSS] = 0.0f;
            ((int*)ws)[WS_AMBCNT] = 0;
        }
    }
}

// ---------------- kernel: per-row ||z||^2, numpy-pairwise bit-exact ----------------
__global__ __launch_bounds__(256) void vq_znorm(const float* __restrict__ z,
                                                float* __restrict__ ws) {
    int tid  = threadIdx.x;
    int lrow = tid >> 5;
    int c    = tid & 31;
    long row = (long)blockIdx.x * 8 + lrow;
    const float* p = z + row * EDIM + (c >> 3) * 128 + (c & 7);
    float r = p[0] * p[0];
    #pragma unroll
    for (int i = 1; i < 16; ++i) {
        float v = p[i * 8];
        r += v * v;
    }
    r += __shfl_xor(r, 1);
    r += __shfl_xor(r, 2);
    r += __shfl_xor(r, 4);
    r += __shfl_xor(r, 8);
    r += __shfl_xor(r, 16);
    if (c == 0) ws[WS_ZNORM + row] = r;
}

// ---------------- kernel: z -> bf16 hi/lo panels ----------------
// layout: [panel p][kc 0..15][plane hi/lo][row 0..127][k 0..31] ushort
__global__ __launch_bounds__(256) void vq_convz(const float* __restrict__ z,
                                                unsigned short* __restrict__ z2) {
    const int tid = threadIdx.x;
    const int p = blockIdx.x;
    const long row0 = (long)p * 128;
    const int row = tid >> 1, half = tid & 1;
    for (int kc = 0; kc < 16; ++kc) {
        const float* src = z + (row0 + row) * EDIM + kc * 32 + half * 16;
        float f[16];
        #pragma unroll
        for (int q = 0; q < 4; ++q) {
            float4 v = ((const float4*)src)[q];
            f[q*4+0] = v.x; f[q*4+1] = v.y; f[q*4+2] = v.z; f[q*4+3] = v.w;
        }
        unsigned hi[8], lo[8];
        #pragma unroll
        for (int q = 0; q < 8; ++q) {
            unsigned short h0 = f2bf(f[2*q]);
            unsigned short h1 = f2bf(f[2*q+1]);
            unsigned short l0 = f2bf(f[2*q]   - bf2f(h0));
            unsigned short l1 = f2bf(f[2*q+1] - bf2f(h1));
            hi[q] = (unsigned)h0 | ((unsigned)h1 << 16);
            lo[q] = (unsigned)l0 | ((unsigned)l1 << 16);
        }
        size_t base = ((size_t)(p * 16 + kc) * 2) * 4096;
        unsigned* dhi = (unsigned*)(z2 + base        + row * 32 + half * 16);
        unsigned* dlo = (unsigned*)(z2 + base + 4096 + row * 32 + half * 16);
        ((uint4*)dhi)[0] = make_uint4(hi[0], hi[1], hi[2], hi[3]);
        ((uint4*)dhi)[1] = make_uint4(hi[4], hi[5], hi[6], hi[7]);
        ((uint4*)dlo)[0] = make_uint4(lo[0], lo[1], lo[2], lo[3]);
        ((uint4*)dlo)[1] = make_uint4(lo[4], lo[5], lo[6], lo[7]);
    }
}

// ---------------- kernel: cb -> bf16 hi/lo panels ----------------
// layout: [cc 0..7][kc 0..15][plane][code 0..127][k 0..31]
__global__ __launch_bounds__(256) void vq_convcb(const float* __restrict__ cb,
                                                 unsigned short* __restrict__ e2) {
    const int tid = threadIdx.x;
    const int cc = blockIdx.x;
    const int row = tid >> 1, half = tid & 1;
    for (int kc = 0; kc < 16; ++kc) {
        const float* src = cb + (size_t)(cc * 128 + row) * EDIM + kc * 32 + half * 16;
        float f[16];
        #pragma unroll
        for (int q = 0; q < 4; ++q) {
            float4 v = ((const float4*)src)[q];
            f[q*4+0] = v.x; f[q*4+1] = v.y; f[q*4+2] = v.z; f[q*4+3] = v.w;
        }
        unsigned hi[8], lo[8];
        #pragma unroll
        for (int q = 0; q < 8; ++q) {
            unsigned short h0 = f2bf(f[2*q]);
            unsigned short h1 = f2bf(f[2*q+1]);
            unsigned short l0 = f2bf(f[2*q]   - bf2f(h0));
            unsigned short l1 = f2bf(f[2*q+1] - bf2f(h1));
            hi[q] = (unsigned)h0 | ((unsigned)h1 << 16);
            lo[q] = (unsigned)l0 | ((unsigned)l1 << 16);
        }
        size_t base = ((size_t)(cc * 16 + kc) * 2) * 4096;
        unsigned* dhi = (unsigned*)(e2 + base        + row * 32 + half * 16);
        unsigned* dlo = (unsigned*)(e2 + base + 4096 + row * 32 + half * 16);
        ((uint4*)dhi)[0] = make_uint4(hi[0], hi[1], hi[2], hi[3]);
        ((uint4*)dhi)[1] = make_uint4(hi[4], hi[5], hi[6], hi[7]);
        ((uint4*)dlo)[0] = make_uint4(lo[0], lo[1], lo[2], lo[3]);
        ((uint4*)dlo)[1] = make_uint4(lo[4], lo[5], lo[6], lo[7]);
    }
}

// ---------------- main MFMA kernel: d-hat + per-row top2 + ambiguity ----------------
// block tile 128 rows x 128 codes (per cc), wave tile 64x64, mfma 16x16x32 bf16
__global__ __launch_bounds__(256, 2) void vq_mfma(const unsigned short* __restrict__ z2,
                                                  const unsigned short* __restrict__ e2,
                                                  const float* __restrict__ ws,
                                                  int* __restrict__ winner,
                                                  int* __restrict__ amb_count,
                                                  int* __restrict__ amb_list) {
    __shared__ unsigned short stage[16384];   // 32 KB: z chunk (16KB) + e chunk (16KB)
    __shared__ float fv1[2][128];
    __shared__ float fv2[2][128];
    __shared__ int   fc1[2][128];

    const int tid = threadIdx.x;
    const int lane = tid & 63, w = tid >> 6;
    const int rw = (w & 1) * 64, cw = (w >> 1) * 64;
    const int ml = lane & 15, kg = lane >> 4;
    const long row0 = (long)blockIdx.x * 128;
    const float* __restrict__ enorm = ws + WS_ENORM;

    float v1[16], v2[16];
    int   c1[16];
    #pragma unroll
    for (int i = 0; i < 16; ++i) { v1[i] = INFINITY; v2[i] = INFINITY; c1[i] = 0; }

    const unsigned short* zt = stage;
    const unsigned short* et = stage + 8192;

    for (int cc = 0; cc < 8; ++cc) {
        f32x4 acc[4][4];
        #pragma unroll
        for (int rt = 0; rt < 4; ++rt)
            #pragma unroll
            for (int ct = 0; ct < 4; ++ct)
                acc[rt][ct] = (f32x4){0.f, 0.f, 0.f, 0.f};

        for (int kc = 0; kc < 16; ++kc) {
            __syncthreads();
            const uint4* zsrc = (const uint4*)(z2 + (size_t)(blockIdx.x * 16 + kc) * 8192);
            const uint4* esrc = (const uint4*)(e2 + (size_t)(cc * 16 + kc) * 8192);
            uint4* st = (uint4*)stage;
#if defined(__has_builtin) && __has_builtin(__builtin_amdgcn_global_load_lds)
            #pragma unroll
            for (int it = 0; it < 4; ++it) {
                int base = it * 256 + w * 64;     // wave-uniform LDS base; lane x16B
                __builtin_amdgcn_global_load_lds(AS1C(zsrc + base + lane), AS3(st + base), 16, 0, 0);
            }
            #pragma unroll
            for (int it = 0; it < 4; ++it) {
                int base = it * 256 + w * 64;
                __builtin_amdgcn_global_load_lds(AS1C(esrc + base + lane), AS3(st + 1024 + base), 16, 0, 0);
            }
#else
            #pragma unroll
            for (int it = 0; it < 4; ++it) {
                int i = it * 256 + tid;
                st[i] = zsrc[i];
            }
            #pragma unroll
            for (int it = 0; it < 4; ++it) {
                int i = it * 256 + tid;
                st[1024 + i] = esrc[i];
            }
#endif
            __syncthreads();

            short8 a[4][2], b[4][2];
            #pragma unroll
            for (int rt = 0; rt < 4; ++rt) {
                a[rt][0] = *(const short8*)&zt[        (rw + rt * 16 + ml) * 32 + kg * 8];
                a[rt][1] = *(const short8*)&zt[4096 + (rw + rt * 16 + ml) * 32 + kg * 8];
            }
            #pragma unroll
            for (int ct = 0; ct < 4; ++ct) {
                b[ct][0] = *(const short8*)&et[        (cw + ct * 16 + ml) * 32 + kg * 8];
                b[ct][1] = *(const short8*)&et[4096 + (cw + ct * 16 + ml) * 32 + kg * 8];
            }
            #pragma unroll
            for (int rt = 0; rt < 4; ++rt)
                #pragma unroll
                for (int ct = 0; ct < 4; ++ct) {
                    acc[rt][ct] = __builtin_amdgcn_mfma_f32_16x16x32_bf16(a[rt][0], b[ct][0], acc[rt][ct], 0, 0, 0);
                    acc[rt][ct] = __builtin_amdgcn_mfma_f32_16x16x32_bf16(a[rt][0], b[ct][1], acc[rt][ct], 0, 0, 0);
                    acc[rt][ct] = __builtin_amdgcn_mfma_f32_16x16x32_bf16(a[rt][1], b[ct][0], acc[rt][ct], 0, 0, 0);
                }
        }

        // epilogue: d-hat = enorm - 2*dot, per-lane top2 per row
        float en[4];
        #pragma unroll
        for (int ct = 0; ct < 4; ++ct) en[ct] = enorm[cc * 128 + cw + ct * 16 + ml];
        #pragma unroll
        for (int rt = 0; rt < 4; ++rt)
            #pragma unroll
            for (int ct = 0; ct < 4; ++ct) {
                int code = cc * 128 + cw + ct * 16 + ml;
                #pragma unroll
                for (int reg = 0; reg < 4; ++reg) {
                    float d = fmaf(-2.0f, acc[rt][ct][reg], en[ct]);
                    int i = rt * 4 + reg;
                    bool lt1 = d < v1[i];
                    bool lt2 = d < v2[i];
                    v2[i] = lt1 ? v1[i] : (lt2 ? d : v2[i]);
                    v1[i] = lt1 ? d : v1[i];
                    c1[i] = lt1 ? code : c1[i];
                }
            }
    }

    // cross-lane merge among the 16 lanes (same kg) sharing each row
    #pragma unroll
    for (int i = 0; i < 16; ++i) {
        #pragma unroll
        for (int off = 1; off < 16; off <<= 1) {
            float ov1 = __shfl_xor(v1[i], off);
            int   oc1 = __shfl_xor(c1[i], off);
            float ov2 = __shfl_xor(v2[i], off);
            bool take = (ov1 < v1[i]) || (ov1 == v1[i] && oc1 < c1[i]);
            float nv2 = take ? fminf(v1[i], ov2) : fminf(v2[i], ov1);
            v1[i] = take ? ov1 : v1[i];
            c1[i] = take ? oc1 : c1[i];
            v2[i] = nv2;
        }
    }
    __syncthreads();
    if (ml == 0) {
        #pragma unroll
        for (int i = 0; i < 16; ++i) {
            int row = rw + (i >> 2) * 16 + kg * 4 + (i & 3);
            fv1[w >> 1][row] = v1[i];
            fv2[w >> 1][row] = v2[i];
            fc1[w >> 1][row] = c1[i];
        }
    }
    __syncthreads();
    if (tid < 128) {
        float a1 = fv1[0][tid], a2 = fv2[0][tid];
        int   ac = fc1[0][tid];
        float b1 = fv1[1][tid], b2 = fv2[1][tid];
        int   bc = fc1[1][tid];
        bool take = (b1 < a1) || (b1 == a1 && bc < ac);
        float V1 = take ? b1 : a1;
        int   C1 = take ? bc : ac;
        float V2 = take ? fminf(a1, b2) : fminf(a2, b1);
        winner[row0 + tid] = C1;
        if (V2 - V1 < AMB_EPS) {
            int p = atomicAdd(amb_count, 1);
            if (p < AMB_CAP) amb_list[p] = (int)(row0 + tid);
        }
    }
}

// ---------------- recheck v2: batched exact R2-chain argmin ----------------
// 8 rows/batch staged transposed in LDS; each thread keeps codes {tid,tid+256,
// tid+512,tid+768} with the identical sequential 16x32-chunk association.
#define RB 8
#define ZSR 9   // padded row stride in zs (breaks bank conflicts on staging writes)
__global__ __launch_bounds__(256) void vq_recheck(const float* __restrict__ z,
                                                  const float* __restrict__ cb,
                                                  const float* __restrict__ ws,
                                                  int* __restrict__ winner,
                                                  const int* __restrict__ amb_count,
                                                  const int* __restrict__ amb_list) {
    __shared__ float zs[EDIM * ZSR];     // [k][r] transposed, 18KB
    __shared__ float wred_d[4];
    __shared__ int   wred_i[4];
    const int tid = threadIdx.x;
    const int lane = tid & 63, wv = tid >> 6;
    const float* __restrict__ enorm = ws + WS_ENORM;

    int n = *amb_count;
    bool overflow = (n > AMB_CAP);
    if (overflow) n = N_ROWS;            // safety net: recheck every row
    int nIter = (n + RB - 1) / RB;

    const float* ec[4];
    float en4[4];
    #pragma unroll
    for (int c = 0; c < 4; ++c) {
        ec[c]  = cb + (size_t)(tid + 256 * c) * EDIM;
        en4[c] = enorm[tid + 256 * c];
    }

    for (int ii = blockIdx.x; ii < nIter; ii += gridDim.x) {
        int rows[RB];
        #pragma unroll
        for (int j = 0; j < RB; ++j) {
            int idx = ii * RB + j;
            if (idx >= n) idx = n - 1;
            rows[j] = overflow ? idx : amb_list[idx];
        }
        __syncthreads();
        #pragma unroll
        for (int j = 0; j < RB; ++j) {
            float2 v = *(const float2*)&z[(long)rows[j] * EDIM + tid * 2];
            zs[(tid * 2 + 0) * ZSR + j] = v.x;
            zs[(tid * 2 + 1) * ZSR + j] = v.y;
        }
        __syncthreads();

        float acc[RB][4];
        #pragma unroll
        for (int r = 0; r < RB; ++r)
            #pragma unroll
            for (int c = 0; c < 4; ++c) acc[r][c] = 0.0f;

        for (int k0 = 0; k0 < EDIM; k0 += 32) {
            float ain[RB][4];
            #pragma unroll
            for (int r = 0; r < RB; ++r)
                #pragma unroll
                for (int c = 0; c < 4; ++c) ain[r][c] = 0.0f;
            #pragma unroll
            for (int ks = 0; ks < 32; ks += 8) {
                float er[4][8];
                #pragma unroll
                for (int c = 0; c < 4; ++c) {
                    float4 a = *(const float4*)&ec[c][k0 + ks];
                    float4 b = *(const float4*)&ec[c][k0 + ks + 4];
                    er[c][0]=a.x; er[c][1]=a.y; er[c][2]=a.z; er[c][3]=a.w;
                    er[c][4]=b.x; er[c][5]=b.y; er[c][6]=b.z; er[c][7]=b.w;
                }
                #pragma unroll
                for (int kk = 0; kk < 8; ++kk) {
                    const float* zp = &zs[(k0 + ks + kk) * ZSR];
                    float4 z0 = *(const float4*)zp;       // rows 0..3 (broadcast)
                    float4 z1 = *(const float4*)(zp + 4); // rows 4..7
                    float zr[RB] = {z0.x, z0.y, z0.z, z0.w, z1.x, z1.y, z1.z, z1.w};
                    #pragma unroll
                    for (int r = 0; r < RB; ++r)
                        #pragma unroll
                        for (int c = 0; c < 4; ++c)
                            ain[r][c] = fmaf(zr[r], er[c][kk], ain[r][c]);
                }
            }
            #pragma unroll
            for (int r = 0; r < RB; ++r)
                #pragma unroll
                for (int c = 0; c < 4; ++c) acc[r][c] += ain[r][c];
        }

        // per-row: d = fl(fl(zn+en) - 2*acc), first-index argmin
        #pragma unroll
        for (int r = 0; r < RB; ++r) {
            float zn = ws[WS_ZNORM + rows[r]];
            float bd = INFINITY;
            int   bc = 0;
            #pragma unroll
            for (int c = 0; c < 4; ++c) {        // codes ascending per thread
                float t = zn + en4[c];
                float d = t - 2.0f * acc[r][c];
                if (d < bd) { bd = d; bc = tid + 256 * c; }
            }
            // wave reduce with index tiebreak
            #pragma unroll
            for (int off = 1; off < 64; off <<= 1) {
                float od = __shfl_xor(bd, off);
                int   oi = __shfl_xor(bc, off);
                if (od < bd || (od == bd && oi < bc)) { bd = od; bc = oi; }
            }
            if (lane == 0) { wred_d[wv] = bd; wred_i[wv] = bc; }
            __syncthreads();
            if (tid == 0) {
                float fd = wred_d[0]; int fi = wred_i[0];
                #pragma unroll
                for (int t2 = 1; t2 < 4; ++t2) {
                    if (wred_d[t2] < fd || (wred_d[t2] == fd && wred_i[t2] < fi)) {
                        fd = wred_d[t2]; fi = wred_i[t2];
                    }
                }
                winner[rows[r]] = fi;
            }
            __syncthreads();
        }
    }
}

// ---------------- emit: idx, counts, z_q_st, loss ----------------
__global__ __launch_bounds__(256) void vq_emit(const float* __restrict__ z,
                                               const float* __restrict__ cb,
                                               const int* __restrict__ winner,
                                               float* __restrict__ ws,
                                               float* __restrict__ out_zq,
                                               float* __restrict__ out_idx) {
    __shared__ float lred[4];
    const int tid = threadIdx.x;
    const long row0 = (long)blockIdx.x * 128;
    if (tid < 128) {
        int wi = winner[row0 + tid];
        out_idx[row0 + tid] = (float)wi;
        atomicAdd(&ws[WS_COUNTS + wi], 1.0f);
    }
    float lsum = 0.0f;
    for (int r = 0; r < 128; ++r) {
        int wv = winner[row0 + r];
        float2 e  = *(const float2*)&cb[(size_t)wv * EDIM + tid * 2];
        float2 zz = *(const float2*)&z[(row0 + r) * EDIM + tid * 2];
        float d0 = e.x - zz.x, d1 = e.y - zz.y;
        float2 o; o.x = zz.x + d0; o.y = zz.y + d1;
        *(float2*)&out_zq[(row0 + r) * EDIM + tid * 2] = o;
        lsum = fmaf(d0, d0, fmaf(d1, d1, lsum));
    }
    #pragma unroll
    for (int off = 32; off > 0; off >>= 1) lsum += __shfl_down(lsum, off);
    int wave = tid >> 6, lane = tid & 63;
    if (lane == 0) lred[wave] = lsum;
    __syncthreads();
    if (tid == 0) atomicAdd(&ws[WS_LOSS], lred[0] + lred[1] + lred[2] + lred[3]);
}

// ---------------- finalize loss + perplexity ----------------
__global__ __launch_bounds__(1024) void vq_final(const float* __restrict__ ws,
                                                 float* __restrict__ out,
                                                 long off_perp) {
    int tid = threadIdx.x;
    float c = ws[WS_COUNTS + tid] * (1.0f / (float)N_ROWS);
    float t = c * logf(c + 1e-10f);
    #pragma unroll
    for (int off = 32; off > 0; off >>= 1) t += __shfl_down(t, off);
    __shared__ float ls[16];
    int wave = tid >> 6, lane = tid & 63;
    if (lane == 0) ls[wave] = t;
    __syncthreads();
    if (tid == 0) {
        float h = 0.0f;
        #pragma unroll
        for (int i = 0; i < 16; ++i) h += ls[i];
        out[off_perp] = expf(-h);
        out[0] = ws[WS_LOSS] * 1.25f / (float)((long)N_ROWS * EDIM);
    }
}

// ================= fallback: round-2 verified fp32 main kernel =================
#define ROWS_PER_BLOCK 128
#define CODE_CHUNK     64
#define KCHUNK         32
#define ZSTRIDE        132
#define ESTRIDE        68

__global__ __launch_bounds__(256) void vq_main_fb(const float* __restrict__ z,
                                                  const float* __restrict__ cb,
                                                  float* __restrict__ ws,
                                                  float* __restrict__ out_zq,
                                                  float* __restrict__ out_idx) {
    __shared__ float zt[KCHUNK * ZSTRIDE];
    __shared__ float et[KCHUNK * ESTRIDE];
    __shared__ float red_d[ROWS_PER_BLOCK * 8];
    __shared__ int   red_i[ROWS_PER_BLOCK * 8];
    __shared__ int   winner[ROWS_PER_BLOCK];
    __shared__ float lred[4];

    const int tid = threadIdx.x;
    const int tx = tid & 7;
    const int ty = tid >> 3;
    const long row0 = (long)blockIdx.x * ROWS_PER_BLOCK;
    const float* __restrict__ enorm = ws + WS_ENORM;
    const float* __restrict__ znorm = ws + WS_ZNORM;

    float zn[4];
    #pragma unroll
    for (int i = 0; i < 4; ++i) zn[i] = znorm[row0 + ty * 4 + i];

    float best[4];
    int   bidx[4];
    #pragma unroll
    for (int i = 0; i < 4; ++i) { best[i] = INFINITY; bidx[i] = 0; }

    const int kq    = (tid & 7) * 4;
    const int rbase = tid >> 3;

    for (int c = 0; c < NCODES; c += CODE_CHUNK) {
        float acc[4][8];
        #pragma unroll
        for (int i = 0; i < 4; ++i)
            #pragma unroll
            for (int j = 0; j < 8; ++j) acc[i][j] = 0.0f;

        for (int k0 = 0; k0 < EDIM; k0 += KCHUNK) {
            __syncthreads();
            #pragma unroll
            for (int it = 0; it < 4; ++it) {
                int r = rbase + it * 32;
                float4 v = *(const float4*)&z[(row0 + r) * EDIM + k0 + kq];
                zt[(kq + 0) * ZSTRIDE + r] = v.x;
                zt[(kq + 1) * ZSTRIDE + r] = v.y;
                zt[(kq + 2) * ZSTRIDE + r] = v.z;
                zt[(kq + 3) * ZSTRIDE + r] = v.w;
            }
            #pragma unroll
            for (int it = 0; it < 2; ++it) {
                int e = rbase + it * 32;
                float4 v = *(const float4*)&cb[(size_t)(c + e) * EDIM + k0 + kq];
                et[(kq + 0) * ESTRIDE + e] = v.x;
                et[(kq + 1) * ESTRIDE + e] = v.y;
                et[(kq + 2) * ESTRIDE + e] = v.z;
                et[(kq + 3) * ESTRIDE + e] = v.w;
            }
            __syncthreads();
            float ain[4][8];
            #pragma unroll
            for (int i = 0; i < 4; ++i)
                #pragma unroll
                for (int j = 0; j < 8; ++j) ain[i][j] = 0.0f;
            #pragma unroll
            for (int kk = 0; kk < KCHUNK; ++kk) {
                float4 zv = *(const float4*)&zt[kk * ZSTRIDE + ty * 4];
                float4 e0 = *(const float4*)&et[kk * ESTRIDE + tx * 8];
                float4 e1 = *(const float4*)&et[kk * ESTRIDE + tx * 8 + 4];
                float za[4] = {zv.x, zv.y, zv.z, zv.w};
                float ea[8] = {e0.x, e0.y, e0.z, e0.w, e1.x, e1.y, e1.z, e1.w};
                #pragma unroll
                for (int i = 0; i < 4; ++i)
                    #pragma unroll
                    for (int j = 0; j < 8; ++j)
                        ain[i][j] = fmaf(za[i], ea[j], ain[i][j]);
            }
            #pragma unroll
            for (int i = 0; i < 4; ++i)
                #pragma unroll
                for (int j = 0; j < 8; ++j) acc[i][j] += ain[i][j];
        }
        #pragma unroll
        for (int j = 0; j < 8; ++j) {
            int code = c + tx * 8 + j;
            float en = enorm[code];
            #pragma unroll
            for (int i = 0; i < 4; ++i) {
                float t = zn[i] + en;
                float d = t - 2.0f * acc[i][j];
                if (d < best[i]) { best[i] = d; bidx[i] = code; }
            }
        }
    }

    __syncthreads();
    #pragma unroll
    for (int i = 0; i < 4; ++i) {
        red_d[(ty * 4 + i) * 8 + tx] = best[i];
        red_i[(ty * 4 + i) * 8 + tx] = bidx[i];
    }
    __syncthreads();
    if (tid < ROWS_PER_BLOCK) {
        float bd = red_d[tid * 8];
        int   bi = red_i[tid * 8];
        #pragma unroll
        for (int t = 1; t < 8; ++t) {
            float dv = red_d[tid * 8 + t];
            int   iv = red_i[tid * 8 + t];
            if (dv < bd || (dv == bd && iv < bi)) { bd = dv; bi = iv; }
        }
        winner[tid] = bi;
        out_idx[row0 + tid] = (float)bi;
        atomicAdd(&ws[WS_COUNTS + bi], 1.0f);
    }
    __syncthreads();

    float lsum = 0.0f;
    for (int r = 0; r < ROWS_PER_BLOCK; ++r) {
        int w = winner[r];
        float2 e  = *(const float2*)&cb[(size_t)w * EDIM + tid * 2];
        float2 zz = *(const float2*)&z[(row0 + r) * EDIM + tid * 2];
        float d0 = e.x - zz.x, d1 = e.y - zz.y;
        float2 o; o.x = zz.x + d0; o.y = zz.y + d1;
        *(float2*)&out_zq[(row0 + r) * EDIM + tid * 2] = o;
        lsum = fmaf(d0, d0, fmaf(d1, d1, lsum));
    }
    #pragma unroll
    for (int off = 32; off > 0; off >>= 1) lsum += __shfl_down(lsum, off);
    int wave = tid >> 6, lane = tid & 63;
    if (lane == 0) lred[wave] = lsum;
    __syncthreads();
    if (tid == 0) atomicAdd(&ws[WS_LOSS], lred[0] + lred[1] + lred[2] + lred[3]);
}

extern "C" void kernel_launch(void* const* d_in, const int* in_sizes, int n_in,
                              void* d_out, int out_size, void* d_ws, size_t ws_size,
                              hipStream_t stream) {
    const float* z  = (const float*)d_in[0];
    const float* cb = (const float*)d_in[1];
    float* out = (float*)d_out;
    float* ws  = (float*)d_ws;

    float* out_zq  = out + 1;
    float* out_idx = out + 1 + (long)N_ROWS * EDIM;
    long   off_perp = 1 + (long)N_ROWS * EDIM + N_ROWS;

    hipLaunchKernelGGL(vq_prep, dim3(NCODES), dim3(256), 0, stream, cb, ws);
    hipLaunchKernelGGL(vq_znorm, dim3(N_ROWS / 8), dim3(256), 0, stream, z, ws);

    if (ws_size >= (size_t)WS_FAST_BYTES) {
        // z2 scratch lives in the z_q output region (16B-aligned at out+4;
        // spills 12 B into the idx region, which emit rewrites afterwards)
        unsigned short* z2 = (unsigned short*)(out + 4);
        unsigned short* e2 = (unsigned short*)((char*)d_ws + WS_E2_OFF);
        int* winner    = ((int*)ws) + WS_WINNER;
        int* amb_count = ((int*)ws) + WS_AMBCNT;
        int* amb_list  = ((int*)ws) + WS_AMBLST;

        hipLaunchKernelGGL(vq_convz, dim3(N_ROWS / 128), dim3(256), 0, stream, z, z2);
        hipLaunchKernelGGL(vq_convcb, dim3(8), dim3(256), 0, stream, cb, e2);
        hipLaunchKernelGGL(vq_mfma, dim3(N_ROWS / 128), dim3(256), 0, stream,
                           z2, e2, ws, winner, amb_count, amb_list);
        hipLaunchKernelGGL(vq_recheck, dim3(512), dim3(256), 0, stream,
                           z, cb, ws, winner, amb_count, amb_list);
        hipLaunchKernelGGL(vq_emit, dim3(N_ROWS / 128), dim3(256), 0, stream,
                           z, cb, winner, ws, out_zq, out_idx);
    } else {
        hipLaunchKernelGGL(vq_main_fb, dim3(N_ROWS / 128), dim3(256), 0, stream,
                           z, cb, ws, out_zq, out_idx);
    }
    hipLaunchKernelGGL(vq_final, dim3(1), dim3(1024), 0, stream, ws, out, off_perp);
}